// Round 5
// baseline (567.988 us; speedup 1.0000x reference)
//
#include <hip/hip_runtime.h>

// Exphormer attention, fp32.
// out[dst] += V[src] * exp(clip(sum_d K[src,h,d]*Q[dst,h,d]/4 * Ee[e,h,d], ±5))
// Ee = edge_attr @ We^T + be

// ---------------- Kernel 1: fused Q/K/V projection ----------------
// Writes Q to Qb[node*64+..], K/V interleaved into KV[node*128 + {0,64}+..]
__global__ __launch_bounds__(256) void proj_kernel(
    const float* __restrict__ x,
    const float* __restrict__ Wq, const float* __restrict__ bq,
    const float* __restrict__ Wk, const float* __restrict__ bk,
    const float* __restrict__ Wv, const float* __restrict__ bv,
    float* __restrict__ Qb, float* __restrict__ KV,
    int n)
{
    __shared__ float WqT[64 * 65];
    __shared__ float WkT[64 * 65];
    __shared__ float WvT[64 * 65];
    __shared__ float xs[4][4][64];

    const int tid  = threadIdx.x;
    const int wave = tid >> 6;
    const int lane = tid & 63;

    #pragma unroll
    for (int k = 0; k < 16; ++k) {
        int idx = tid + k * 256;
        int j = idx >> 6, i = idx & 63;
        WqT[i * 65 + j] = Wq[idx];
        WkT[i * 65 + j] = Wk[idx];
        WvT[i * 65 + j] = Wv[idx];
    }
    const float bqv = bq[lane];
    const float bkv = bk[lane];
    const float bvv = bv[lane];
    __syncthreads();

    for (int blockbase = blockIdx.x * 16; blockbase < n;
         blockbase += gridDim.x * 16) {
        int base = blockbase + wave * 4;
        #pragma unroll
        for (int j = 0; j < 4; ++j) {
            int node = base + j;
            xs[wave][j][lane] = (node < n) ? x[node * 64 + lane] : 0.f;
        }
        __syncthreads();

        float accq[4], acck[4], accv[4];
        #pragma unroll
        for (int j = 0; j < 4; ++j) { accq[j] = bqv; acck[j] = bkv; accv[j] = bvv; }

        #pragma unroll
        for (int f = 0; f < 16; ++f) {
            float wq[4], wk[4], wv[4];
            #pragma unroll
            for (int u = 0; u < 4; ++u) {
                int i = 4 * f + u;
                wq[u] = WqT[i * 65 + lane];
                wk[u] = WkT[i * 65 + lane];
                wv[u] = WvT[i * 65 + lane];
            }
            #pragma unroll
            for (int j = 0; j < 4; ++j) {
                float4 xv = *reinterpret_cast<const float4*>(&xs[wave][j][4 * f]);
                accq[j] = fmaf(xv.x, wq[0], accq[j]);
                accq[j] = fmaf(xv.y, wq[1], accq[j]);
                accq[j] = fmaf(xv.z, wq[2], accq[j]);
                accq[j] = fmaf(xv.w, wq[3], accq[j]);
                acck[j] = fmaf(xv.x, wk[0], acck[j]);
                acck[j] = fmaf(xv.y, wk[1], acck[j]);
                acck[j] = fmaf(xv.z, wk[2], acck[j]);
                acck[j] = fmaf(xv.w, wk[3], acck[j]);
                accv[j] = fmaf(xv.x, wv[0], accv[j]);
                accv[j] = fmaf(xv.y, wv[1], accv[j]);
                accv[j] = fmaf(xv.z, wv[2], accv[j]);
                accv[j] = fmaf(xv.w, wv[3], accv[j]);
            }
        }

        #pragma unroll
        for (int j = 0; j < 4; ++j) {
            int node = base + j;
            if (node < n) {
                Qb[(size_t)node * 64 + lane]       = accq[j];
                KV[(size_t)node * 128 + lane]      = acck[j];
                KV[(size_t)node * 128 + 64 + lane] = accv[j];
            }
        }
        __syncthreads();
    }
}

// ---------------- Kernel 2: per-edge attention + scatter ----------------
// block 256 = 4 independent waves, no block barriers in the loop.
// 2 edges per wave per iteration. Software pipeline:
//   ei prefetched 2 iterations ahead (so gather addresses are ready),
//   K/V/Q gathers + ea row prefetched 1 iteration ahead,
//   -> the 128-FMA matvec + score/scatter of iter t hides gather latency
//      of iter t+1.
// We row pinned in 64 registers via empty-asm (round-4 proven).
__global__ __launch_bounds__(256, 4) void edge_kernel(
    const float* __restrict__ ea, const int* __restrict__ ei,
    const float* __restrict__ Qb, const float* __restrict__ KV,
    const float* __restrict__ We, const float* __restrict__ be,
    float* __restrict__ out, int EG)
{
    __shared__ float eas[4][128];    // per-wave: 2 staged ea rows

    const int tid  = threadIdx.x;
    const int wave = tid >> 6;
    const int lane = tid & 63;

    // We row for output dim `lane` -> 64 pinned registers
    float wr[64];
    {
        const float4* wrow = reinterpret_cast<const float4*>(We + (size_t)lane * 64);
        #pragma unroll
        for (int f = 0; f < 16; ++f) {
            float4 t4 = wrow[f];
            wr[4 * f + 0] = t4.x;
            wr[4 * f + 1] = t4.y;
            wr[4 * f + 2] = t4.z;
            wr[4 * f + 3] = t4.w;
        }
    }
    #pragma unroll
    for (int i = 0; i < 64; ++i)
        asm volatile("" : "+v"(wr[i]));   // opaque: cannot be rematerialized
    const float bias = be[lane];

    const int nw   = gridDim.x * 4;
    const int wid  = blockIdx.x * 4 + __builtin_amdgcn_readfirstlane(wave);
    const int step = nw * 2;

    int base = wid * 2;
    if (base >= EG) return;

    // ---- prologue: load t0 fully, t1 indices ----
    int2   sc  = *reinterpret_cast<const int2*>(&ei[base]);
    int2   dc  = *reinterpret_cast<const int2*>(&ei[EG + base]);
    float2 eac = *reinterpret_cast<const float2*>(&ea[(size_t)base * 64 + 2 * lane]);
    float kv0 = KV[(size_t)sc.x * 128 + lane];
    float vv0 = KV[(size_t)sc.x * 128 + 64 + lane];
    float qv0 = Qb[(size_t)sc.x * 0 + (size_t)dc.x * 64 + lane];
    float kv1 = 0.f, vv1 = 0.f, qv1 = 0.f;
    if (base + 1 < EG) {
        kv1 = KV[(size_t)sc.y * 128 + lane];
        vv1 = KV[(size_t)sc.y * 128 + 64 + lane];
        qv1 = Qb[(size_t)dc.y * 64 + lane];
    }
    int2 sn = sc, dn = dc;
    if (base + step < EG) {
        sn = *reinterpret_cast<const int2*>(&ei[base + step]);
        dn = *reinterpret_cast<const int2*>(&ei[EG + base + step]);
    }

    for (; base < EG; base += step) {
        // stage current ea pair: lanes cover row e0 (first 32 lanes' float2s)
        // then row e1
        *reinterpret_cast<float2*>(&eas[wave][2 * lane]) = eac;
        __builtin_amdgcn_wave_barrier();

        const int nb1 = base + step;
        const int nb2 = base + 2 * step;

        // prefetch t+2 indices
        int2 snn = sn, dnn = dn;
        if (nb2 < EG) {
            snn = *reinterpret_cast<const int2*>(&ei[nb2]);
            dnn = *reinterpret_cast<const int2*>(&ei[EG + nb2]);
        }
        // prefetch t+1 ea row pair + gathers (addresses ready from last iter)
        float2 ean  = make_float2(0.f, 0.f);
        float kv0n = 0.f, vv0n = 0.f, qv0n = 0.f;
        float kv1n = 0.f, vv1n = 0.f, qv1n = 0.f;
        if (nb1 < EG) {
            ean  = *reinterpret_cast<const float2*>(&ea[(size_t)nb1 * 64 + 2 * lane]);
            kv0n = KV[(size_t)sn.x * 128 + lane];
            vv0n = KV[(size_t)sn.x * 128 + 64 + lane];
            qv0n = Qb[(size_t)dn.x * 64 + lane];
            kv1n = KV[(size_t)sn.y * 128 + lane];
            vv1n = KV[(size_t)sn.y * 128 + 64 + lane];
            qv1n = Qb[(size_t)dn.y * 64 + lane];
        }

        // matvec for both edges: LDS uniform broadcasts x pinned We regs
        float acc0 = bias, acc1 = bias;
        const float4* r0 = reinterpret_cast<const float4*>(&eas[wave][0]);
        const float4* r1 = reinterpret_cast<const float4*>(&eas[wave][64]);
        #pragma unroll
        for (int f = 0; f < 16; ++f) {
            float4 a0 = r0[f];
            float4 a1 = r1[f];
            acc0 = fmaf(a0.x, wr[4 * f + 0], acc0);
            acc0 = fmaf(a0.y, wr[4 * f + 1], acc0);
            acc0 = fmaf(a0.z, wr[4 * f + 2], acc0);
            acc0 = fmaf(a0.w, wr[4 * f + 3], acc0);
            acc1 = fmaf(a1.x, wr[4 * f + 0], acc1);
            acc1 = fmaf(a1.y, wr[4 * f + 1], acc1);
            acc1 = fmaf(a1.z, wr[4 * f + 2], acc1);
            acc1 = fmaf(a1.w, wr[4 * f + 3], acc1);
        }

        // edge 0: score, clip, exp, scatter
        {
            float t = kv0 * qv0 * 0.25f * acc0;
            t += __shfl_xor(t, 1);
            t += __shfl_xor(t, 2);
            t += __shfl_xor(t, 4);
            t += __shfl_xor(t, 8);
            t = fminf(fmaxf(t, -5.f), 5.f);
            float s = __expf(t);
            atomicAdd(&out[(size_t)dc.x * 64 + lane], vv0 * s);
        }
        // edge 1
        if (base + 1 < EG) {
            float t = kv1 * qv1 * 0.25f * acc1;
            t += __shfl_xor(t, 1);
            t += __shfl_xor(t, 2);
            t += __shfl_xor(t, 4);
            t += __shfl_xor(t, 8);
            t = fminf(fmaxf(t, -5.f), 5.f);
            float s = __expf(t);
            atomicAdd(&out[(size_t)dc.y * 64 + lane], vv1 * s);
        }
        __builtin_amdgcn_wave_barrier();   // eas reused next iteration

        // rotate pipeline registers (all statically named)
        sc = sn;  dc = dn;  sn = snn;  dn = dnn;
        eac = ean;
        kv0 = kv0n; vv0 = vv0n; qv0 = qv0n;
        kv1 = kv1n; vv1 = vv1n; qv1 = qv1n;
    }
}

extern "C" void kernel_launch(void* const* d_in, const int* in_sizes, int n_in,
                              void* d_out, int out_size, void* d_ws, size_t ws_size,
                              hipStream_t stream) {
    const float* x   = (const float*)d_in[0];
    const float* ea  = (const float*)d_in[1];
    const int*   ei  = (const int*)d_in[2];
    const float* Wq  = (const float*)d_in[3];
    const float* bq  = (const float*)d_in[4];
    const float* Wk  = (const float*)d_in[5];
    const float* bk  = (const float*)d_in[6];
    const float* We  = (const float*)d_in[7];
    const float* be  = (const float*)d_in[8];
    const float* Wv  = (const float*)d_in[9];
    const float* bv  = (const float*)d_in[10];
    float* out = (float*)d_out;

    const int n  = in_sizes[0] / 64;   // 50000
    const int EG = in_sizes[1] / 64;   // 1600000

    float* Qb = (float*)d_ws;                       // n*64
    float* KV = Qb + (size_t)n * 64;                // n*128 (K|V interleaved)

    hipMemsetAsync(d_out, 0, (size_t)out_size * sizeof(float), stream);

    const int projGrid = (n + 15) / 16;
    proj_kernel<<<projGrid, 256, 0, stream>>>(x, Wq, bq, Wk, bk, Wv, bv,
                                              Qb, KV, n);

    const int edgeGrid = 4096;
    edge_kernel<<<edgeGrid, 256, 0, stream>>>(ea, ei, Qb, KV, We, be,
                                              out, EG);
}

// Round 6
// 562.564 us; speedup vs baseline: 1.0096x; 1.0096x over previous
//
#include <hip/hip_runtime.h>

// Exphormer attention, fp32 accuracy via split-bf16 MFMA.
// out[dst] += V[src] * exp(clip(sum_d K[src,h,d]*Q[dst,h,d]/4 * Ee[e,h,d], ±5))
// Ee = edge_attr @ We^T + be   computed with mfma_f32_16x16x32_bf16,
// inputs split x = hi + lo (Veltkamp, exact), using hi*hi + hi*lo + lo*hi.

typedef __attribute__((ext_vector_type(8))) short bf16x8;   // MFMA A/B frag
typedef __attribute__((ext_vector_type(4))) float f32x4;    // MFMA C/D frag

union frag_u { uint32_t u[4]; bf16x8 v; };

// pack two f32 (truncated to bf16) into one dword; a -> low half (lower k)
__device__ __forceinline__ uint32_t pack2(float a, float b) {
    return (__float_as_uint(a) >> 16) | (__float_as_uint(b) & 0xffff0000u);
}

// float4 -> 2 hi dwords + 2 lo dwords (bf16 pairs). hi exact-truncate, lo = x-hi exact.
__device__ __forceinline__ void cvt4(float4 v, uint32_t& h0, uint32_t& h1,
                                     uint32_t& l0, uint32_t& l1) {
    float hx = __uint_as_float(__float_as_uint(v.x) & 0xffff0000u);
    float hy = __uint_as_float(__float_as_uint(v.y) & 0xffff0000u);
    float hz = __uint_as_float(__float_as_uint(v.z) & 0xffff0000u);
    float hw = __uint_as_float(__float_as_uint(v.w) & 0xffff0000u);
    h0 = pack2(v.x, v.y);
    h1 = pack2(v.z, v.w);
    l0 = pack2(v.x - hx, v.y - hy);
    l1 = pack2(v.z - hz, v.w - hw);
}

// ---------------- Kernel 1: fused Q/K/V projection ----------------
// Qb[node*64+d]; K/V interleaved: KV[node*128 + d] (K), KV[node*128+64+d] (V)
__global__ __launch_bounds__(256) void proj_kernel(
    const float* __restrict__ x,
    const float* __restrict__ Wq, const float* __restrict__ bq,
    const float* __restrict__ Wk, const float* __restrict__ bk,
    const float* __restrict__ Wv, const float* __restrict__ bv,
    float* __restrict__ Qb, float* __restrict__ KV,
    int n)
{
    __shared__ float WqT[64 * 65];
    __shared__ float WkT[64 * 65];
    __shared__ float WvT[64 * 65];
    __shared__ float xs[4][4][64];

    const int tid  = threadIdx.x;
    const int wave = tid >> 6;
    const int lane = tid & 63;

    #pragma unroll
    for (int k = 0; k < 16; ++k) {
        int idx = tid + k * 256;
        int j = idx >> 6, i = idx & 63;
        WqT[i * 65 + j] = Wq[idx];
        WkT[i * 65 + j] = Wk[idx];
        WvT[i * 65 + j] = Wv[idx];
    }
    const float bqv = bq[lane];
    const float bkv = bk[lane];
    const float bvv = bv[lane];
    __syncthreads();

    for (int blockbase = blockIdx.x * 16; blockbase < n;
         blockbase += gridDim.x * 16) {
        int base = blockbase + wave * 4;
        #pragma unroll
        for (int j = 0; j < 4; ++j) {
            int node = base + j;
            xs[wave][j][lane] = (node < n) ? x[node * 64 + lane] : 0.f;
        }
        __syncthreads();

        float accq[4], acck[4], accv[4];
        #pragma unroll
        for (int j = 0; j < 4; ++j) { accq[j] = bqv; acck[j] = bkv; accv[j] = bvv; }

        #pragma unroll
        for (int f = 0; f < 16; ++f) {
            float wq[4], wk[4], wv[4];
            #pragma unroll
            for (int u = 0; u < 4; ++u) {
                int i = 4 * f + u;
                wq[u] = WqT[i * 65 + lane];
                wk[u] = WkT[i * 65 + lane];
                wv[u] = WvT[i * 65 + lane];
            }
            #pragma unroll
            for (int j = 0; j < 4; ++j) {
                float4 xv = *reinterpret_cast<const float4*>(&xs[wave][j][4 * f]);
                accq[j] = fmaf(xv.x, wq[0], accq[j]);
                accq[j] = fmaf(xv.y, wq[1], accq[j]);
                accq[j] = fmaf(xv.z, wq[2], accq[j]);
                accq[j] = fmaf(xv.w, wq[3], accq[j]);
                acck[j] = fmaf(xv.x, wk[0], acck[j]);
                acck[j] = fmaf(xv.y, wk[1], acck[j]);
                acck[j] = fmaf(xv.z, wk[2], acck[j]);
                acck[j] = fmaf(xv.w, wk[3], acck[j]);
                accv[j] = fmaf(xv.x, wv[0], accv[j]);
                accv[j] = fmaf(xv.y, wv[1], accv[j]);
                accv[j] = fmaf(xv.z, wv[2], accv[j]);
                accv[j] = fmaf(xv.w, wv[3], accv[j]);
            }
        }

        #pragma unroll
        for (int j = 0; j < 4; ++j) {
            int node = base + j;
            if (node < n) {
                Qb[(size_t)node * 64 + lane]       = accq[j];
                KV[(size_t)node * 128 + lane]      = acck[j];
                KV[(size_t)node * 128 + 64 + lane] = accv[j];
            }
        }
        __syncthreads();
    }
}

// ---------------- Kernel 2: per-edge attention via MFMA ----------------
// 4 independent waves/block, no LDS, no barriers. Each wave: 16-edge tile.
//   A = ea tile [16 x 64], B[k][n] = We[n][k], Ee = A*B + be  (3 split MFMAs
//   per (nt,ks); nt = head tile 0..3, ks = K-step 0..1).
// Fragment layouts (gfx950, 16x16x32 bf16):
//   A: lane(q=l&15,g=l>>4): row m=q, k = 32ks + 16b + 4g + j   (b: elems 0-3/4-7)
//   B: lane: col n=q,        k = 32ks + 16b + 4g + j
//   C: lane: col n=q,        row e = 4g + reg                  (verified m89)
// So lane holds Ee[4 edges][head nt][d=q] -> score reduce = shfl_xor over
// the 16-lane group, exactly like prior rounds.
__global__ __launch_bounds__(256) void edge_kernel(
    const float* __restrict__ ea, const int* __restrict__ ei,
    const float* __restrict__ Qb, const float* __restrict__ KV,
    const float* __restrict__ We, const float* __restrict__ be,
    float* __restrict__ out, int EG)
{
    const int tid  = threadIdx.x;
    const int lane = tid & 63;
    const int g    = lane >> 4;
    const int q    = lane & 15;

    // ---- B fragments (We), built once: Bh/Bl[nt][ks] ----
    frag_u Bh[4][2], Bl[4][2];
    #pragma unroll
    for (int nt = 0; nt < 4; ++nt) {
        #pragma unroll
        for (int ks = 0; ks < 2; ++ks) {
            #pragma unroll
            for (int b = 0; b < 2; ++b) {
                float4 w4 = *reinterpret_cast<const float4*>(
                    &We[(size_t)(16 * nt + q) * 64 + 32 * ks + 16 * b + 4 * g]);
                cvt4(w4, Bh[nt][ks].u[2 * b + 0], Bh[nt][ks].u[2 * b + 1],
                         Bl[nt][ks].u[2 * b + 0], Bl[nt][ks].u[2 * b + 1]);
            }
        }
    }
    float bias[4];
    #pragma unroll
    for (int nt = 0; nt < 4; ++nt) bias[nt] = be[16 * nt + q];

    const int nwaves = gridDim.x * 4;
    const int wid    = blockIdx.x * 4 + (tid >> 6);

    for (int eb = wid * 16; eb < EG; eb += nwaves * 16) {
        const int eld = min(eb + q, EG - 1);      // EG%16==0 in practice
        const int se  = ei[eld];
        const int de  = ei[EG + eld];

        // ---- A fragments straight from global (coalesced per 64B line) ----
        frag_u Ah[2], Al[2];
        const float* arow = &ea[(size_t)eld * 64];
        #pragma unroll
        for (int ks = 0; ks < 2; ++ks) {
            #pragma unroll
            for (int b = 0; b < 2; ++b) {
                float4 a4 = *reinterpret_cast<const float4*>(
                    &arow[32 * ks + 16 * b + 4 * g]);
                cvt4(a4, Ah[ks].u[2 * b + 0], Ah[ks].u[2 * b + 1],
                         Al[ks].u[2 * b + 0], Al[ks].u[2 * b + 1]);
            }
        }

        // ---- Ee = ea @ We^T + be via split-bf16 MFMA ----
        f32x4 acc[4];
        #pragma unroll
        for (int nt = 0; nt < 4; ++nt) {
            acc[nt][0] = bias[nt]; acc[nt][1] = bias[nt];
            acc[nt][2] = bias[nt]; acc[nt][3] = bias[nt];
            #pragma unroll
            for (int ks = 0; ks < 2; ++ks) {
                acc[nt] = __builtin_amdgcn_mfma_f32_16x16x32_bf16(
                              Al[ks].v, Bh[nt][ks].v, acc[nt], 0, 0, 0);
                acc[nt] = __builtin_amdgcn_mfma_f32_16x16x32_bf16(
                              Ah[ks].v, Bl[nt][ks].v, acc[nt], 0, 0, 0);
                acc[nt] = __builtin_amdgcn_mfma_f32_16x16x32_bf16(
                              Ah[ks].v, Bh[nt][ks].v, acc[nt], 0, 0, 0);
            }
        }

        // ---- score + scatter; edge e = eb + 4g + r ----
        #pragma unroll
        for (int r = 0; r < 4; ++r) {
            const int srcr = __shfl(se, 4 * g + r);
            const int dstr = __shfl(de, 4 * g + r);
            const bool act = (eb + 4 * g + r) < EG;
            const float* kb = KV + (size_t)srcr * 128 + q;
            const float* qp = Qb + (size_t)dstr * 64 + q;

            float s_[4];
            #pragma unroll
            for (int nt = 0; nt < 4; ++nt) {
                float kv = kb[16 * nt];
                float qv = qp[16 * nt];
                float t  = kv * qv * (0.25f * acc[nt][r]);
                t += __shfl_xor(t, 1);
                t += __shfl_xor(t, 2);
                t += __shfl_xor(t, 4);
                t += __shfl_xor(t, 8);
                t = fminf(fmaxf(t, -5.f), 5.f);
                s_[nt] = __expf(t);
            }
            if (act) {
                float* ob = out + (size_t)dstr * 64 + q;
                #pragma unroll
                for (int nt = 0; nt < 4; ++nt) {
                    float vv = kb[64 + 16 * nt];
                    atomicAdd(&ob[16 * nt], vv * s_[nt]);
                }
            }
        }
    }
}

extern "C" void kernel_launch(void* const* d_in, const int* in_sizes, int n_in,
                              void* d_out, int out_size, void* d_ws, size_t ws_size,
                              hipStream_t stream) {
    const float* x   = (const float*)d_in[0];
    const float* ea  = (const float*)d_in[1];
    const int*   ei  = (const int*)d_in[2];
    const float* Wq  = (const float*)d_in[3];
    const float* bq  = (const float*)d_in[4];
    const float* Wk  = (const float*)d_in[5];
    const float* bk  = (const float*)d_in[6];
    const float* We  = (const float*)d_in[7];
    const float* be  = (const float*)d_in[8];
    const float* Wv  = (const float*)d_in[9];
    const float* bv  = (const float*)d_in[10];
    float* out = (float*)d_out;

    const int n  = in_sizes[0] / 64;   // 50000
    const int EG = in_sizes[1] / 64;   // 1600000

    float* Qb = (float*)d_ws;                       // n*64
    float* KV = Qb + (size_t)n * 64;                // n*128 (K|V interleaved)

    hipMemsetAsync(d_out, 0, (size_t)out_size * sizeof(float), stream);

    const int projGrid = (n + 15) / 16;
    proj_kernel<<<projGrid, 256, 0, stream>>>(x, Wq, bq, Wk, bk, Wv, bv,
                                              Qb, KV, n);

    const int edgeGrid = 4096;
    edge_kernel<<<edgeGrid, 256, 0, stream>>>(ea, ei, Qb, KV, We, be,
                                              out, EG);
}